// Round 6
// baseline (79.136 us; speedup 1.0000x reference)
//
#include <hip/hip_runtime.h>
#include <math.h>

// Problem dims (fixed by setup_inputs)
#define B_ 4
#define G_ 8
#define D_ 8
#define H_ 256
#define W_ 320
#define N_ 9
constexpr int HW  = H_ * W_;
constexpr int DHW = D_ * HW;
constexpr int BHW = B_ * HW;
constexpr float BN_EPS = 1e-5f;

// d_ws float layout:
//   [0..127]    fw0[16][8]   (BN-folded layer0 weights)
//   [128..143]  fb0[16]      (BN-folded layer0 bias)
//   [144..271]  fw1[8][16]
//   [272..279]  fb1[8]
//   [280..287]  fw2[8]
//   [288]       fb2
//   [292..295]  sc[B]        (xnorm scale per batch)
//   [296..299]  ofs[B]       (xnorm offset per batch)
//   [320...]    pair planes: float4 plane[4][B*HW], plane j holds
//               {xn(2j), s(2j), xn(2j+1), s(2j+1)} for each pixel (21.0 MB)
#define WS_PAIR_OFF 320

// XCD band swizzle: hardware dispatches blockIdx round-robin to 8 XCDs
// (xcd = bid % 8). Remap so each XCD owns a contiguous pixel band ->
// its plane slice stays resident in its 4 MiB L2 across all 9 neighbor
// passes. nblocks must be divisible by 8.
__device__ __forceinline__ int swz_band(int bid, int per_xcd) {
    return (bid & 7) * per_xcd + (bid >> 3);
}

// ---------------- Kernel 0: fold BN into weights, precompute xnorm affine ----------------
__global__ void k_setup(
    const float* __restrict__ dmin, const float* __restrict__ dmax,
    const float* __restrict__ w0, const float* __restrict__ g0, const float* __restrict__ b0,
    const float* __restrict__ m0, const float* __restrict__ v0,
    const float* __restrict__ w1, const float* __restrict__ g1, const float* __restrict__ b1,
    const float* __restrict__ m1, const float* __restrict__ v1,
    const float* __restrict__ w2, const float* __restrict__ b2,
    float* __restrict__ ws)
{
    int t = threadIdx.x;
    if (t < 16) {
        float inv   = g0[t] * rsqrtf(v0[t] + BN_EPS);
        float shift = b0[t] - m0[t] * inv;
        for (int g = 0; g < G_; ++g) ws[t * G_ + g] = w0[t * G_ + g] * inv;
        ws[128 + t] = shift;
    }
    if (t < 8) {
        float inv   = g1[t] * rsqrtf(v1[t] + BN_EPS);
        float shift = b1[t] - m1[t] * inv;
        for (int i = 0; i < 16; ++i) ws[144 + t * 16 + i] = w1[t * 16 + i] * inv;
        ws[272 + t] = shift;
        ws[280 + t] = w2[t];
    }
    if (t == 0) ws[288] = b2[0];
    if (t < B_) {
        float imin = 1.0f / dmin[t];
        float imax = 1.0f / dmax[t];
        float sc   = 1.0f / (imin - imax);
        ws[292 + t] = sc;
        ws[296 + t] = -imax * sc;
    }
}

// ---------------- MLP for one pixel-depth: G costs -> s ----------------
__device__ __forceinline__ float mlp_eval(const float c[G_], const float* __restrict__ ws) {
    float h0[16];
#pragma unroll
    for (int o = 0; o < 16; ++o) {
        float acc = ws[128 + o];
#pragma unroll
        for (int g = 0; g < G_; ++g) acc = fmaf(c[g], ws[o * G_ + g], acc);
        h0[o] = fmaxf(acc, 0.0f);
    }
    float h1[8];
#pragma unroll
    for (int o = 0; o < 8; ++o) {
        float acc = ws[272 + o];
#pragma unroll
        for (int i = 0; i < 16; ++i) acc = fmaf(h0[i], ws[144 + o * 16 + i], acc);
        h1[o] = fmaxf(acc, 0.0f);
    }
    float s = ws[288];
#pragma unroll
    for (int i = 0; i < 8; ++i) s = fmaf(h1[i], ws[280 + i], s);
    return s;
}

// ---------------- Kernel 1: one thread per (pixel, depth-pair) ----------------
// tid = (b*HW + pix) * 4 + j, handles depths 2j and 2j+1, writes plane[j].
// 5120 blocks: XCD k covers pixels [k*40960, (k+1)*40960) — same bands as k_aggregate.
__global__ __launch_bounds__(256) void k_s_xnorm(
    const float* __restrict__ cost,      // [B,G,D,H,W]
    const float* __restrict__ dsamp,     // [B,D,H,W]
    const float* __restrict__ ws,
    float4* __restrict__ plane)          // [4][B*HW]
{
    int tid = swz_band(blockIdx.x, 640) * 256 + threadIdx.x;  // over B*HW*4
    int j   = tid & 3;
    int idx = tid >> 2;          // b*HW + pix
    int b   = idx / HW;
    int pix = idx % HW;
    int d0  = j * 2;

    float sc  = ws[292 + b];
    float ofs = ws[296 + b];

    const float* cb = cost  + (size_t)b * G_ * DHW + (size_t)d0 * HW + pix;
    const float* db = dsamp + (size_t)b * DHW + (size_t)d0 * HW + pix;

    float c0[G_], c1[G_];
#pragma unroll
    for (int g = 0; g < G_; ++g) {
        c0[g] = cb[(size_t)g * DHW];
        c1[g] = cb[(size_t)g * DHW + HW];
    }

    float s0 = mlp_eval(c0, ws);
    float s1 = mlp_eval(c1, ws);

    float4 res;
    res.x = fmaf(__builtin_amdgcn_rcpf(db[0]),  sc, ofs);
    res.y = s0;
    res.z = fmaf(__builtin_amdgcn_rcpf(db[HW]), sc, ofs);
    res.w = s1;

    plane[(size_t)j * BHW + idx] = res;
}

// ---------------- Kernel 2: neighbor gather + sigmoid kernel + aggregate ----------------
// 2 threads per pixel: even lane (half=0) does neighbors 0,2,4,6,8; odd lane
// 1,3,5,7. All grid/fw loads for a thread's neighbors are issued up front
// (independent HBM misses overlap). Partial acc reduced across the lane pair
// via __shfl_xor, even lane stores.
__global__ __launch_bounds__(256) void k_aggregate(
    const float* __restrict__ grid,      // [B, N*H, W, 2]
    const float* __restrict__ fweight,   // [B, N, H, W]
    const float4* __restrict__ plane,    // [4][B*HW]
    float* __restrict__ out)             // [B,D,H,W]
{
    int tid  = swz_band(blockIdx.x, 320) * 256 + threadIdx.x;  // over B*HW*2
    int half = tid & 1;
    int idx  = tid >> 1;          // b*HW + pix
    int b    = idx / HW;
    int pix  = idx % HW;
    int h    = pix / W_;
    int wq   = pix % W_;

    // ---- prefetch grid + fw for my neighbors (independent loads) ----
    float gx[5], gy[5], fwv[5];
    const float2* gp = (const float2*)grid;
#pragma unroll
    for (int k = 0; k < 5; ++k) {
        int n = 2 * k + half;
        if (n < N_) {
            float2 g = gp[(b * (N_ * H_) + n * H_ + h) * W_ + wq];
            gx[k]  = g.x;
            gy[k]  = g.y;
            fwv[k] = fweight[((b * N_ + n) * H_ + h) * W_ + wq];
        }
    }

    // ---- center xnorm per depth (one coalesced float4 per plane) ----
    float xnc[D_];
#pragma unroll
    for (int j = 0; j < 4; ++j) {
        float4 v = plane[(size_t)j * BHW + idx];
        xnc[2 * j]     = v.x;
        xnc[2 * j + 1] = v.z;
    }

    float acc[D_];
#pragma unroll
    for (int d = 0; d < D_; ++d) acc[d] = 0.0f;

    const int bbase = b * HW;

#pragma unroll
    for (int k = 0; k < 5; ++k) {
        int n = 2 * k + half;
        if (n >= N_) continue;   // only k=4 on odd lanes

        // align_corners=False, border padding
        float gxp = fminf(fmaxf((gx[k] + 1.0f) * 0.5f * W_ - 0.5f, 0.0f), (float)(W_ - 1));
        float gyp = fminf(fmaxf((gy[k] + 1.0f) * 0.5f * H_ - 0.5f, 0.0f), (float)(H_ - 1));
        float x0f = floorf(gxp);
        float y0f = floorf(gyp);
        float wx = gxp - x0f;
        float wy = gyp - y0f;
        int x0 = (int)x0f;
        int y0 = (int)y0f;
        int x1 = min(x0 + 1, W_ - 1);
        int y1 = min(y0 + 1, H_ - 1);
        float w00 = (1.0f - wx) * (1.0f - wy);
        float w01 = wx * (1.0f - wy);
        float w10 = (1.0f - wx) * wy;
        float w11 = wx * wy;
        float fw = fwv[k];

        int o00 = bbase + y0 * W_ + x0;
        int o01 = bbase + y0 * W_ + x1;
        int o10 = bbase + y1 * W_ + x0;
        int o11 = bbase + y1 * W_ + x1;

#pragma unroll
        for (int j = 0; j < 4; ++j) {
            const float4* pj = plane + (size_t)j * BHW;
            float4 a = pj[o00];
            float4 p = pj[o01];
            float4 q = pj[o10];
            float4 r = pj[o11];
            // depth 2j: components .x (xn), .y (s); depth 2j+1: .z, .w
            float xs0 = w00 * a.x + w01 * p.x + w10 * q.x + w11 * r.x;
            float ss0 = w00 * a.y + w01 * p.y + w10 * q.y + w11 * r.y;
            float xs1 = w00 * a.z + w01 * p.z + w10 * q.z + w11 * r.z;
            float ss1 = w00 * a.w + w01 * p.w + w10 * q.w + w11 * r.w;

            float df0 = fminf(fabsf(xs0 - xnc[2 * j]) * 40.0f, 4.0f);
            float df1 = fminf(fabsf(xs1 - xnc[2 * j + 1]) * 40.0f, 4.0f);
            float dw0 = __builtin_amdgcn_rcpf(1.0f + __expf(2.0f * df0 - 4.0f));
            float dw1 = __builtin_amdgcn_rcpf(1.0f + __expf(2.0f * df1 - 4.0f));
            acc[2 * j]     = fmaf(ss0 * fw, dw0, acc[2 * j]);
            acc[2 * j + 1] = fmaf(ss1 * fw, dw1, acc[2 * j + 1]);
        }
    }

    // ---- reduce across the lane pair, even lane stores ----
#pragma unroll
    for (int d = 0; d < D_; ++d) acc[d] += __shfl_xor(acc[d], 1);

    if (half == 0) {
#pragma unroll
        for (int d = 0; d < D_; ++d) out[(b * D_ + d) * HW + pix] = acc[d];
    }
}

extern "C" void kernel_launch(void* const* d_in, const int* in_sizes, int n_in,
                              void* d_out, int out_size, void* d_ws, size_t ws_size,
                              hipStream_t stream) {
    const float* cost    = (const float*)d_in[0];
    const float* dsamp   = (const float*)d_in[1];
    const float* dmin    = (const float*)d_in[2];
    const float* dmax    = (const float*)d_in[3];
    const float* grid    = (const float*)d_in[4];
    const float* fweight = (const float*)d_in[5];
    const float* w0 = (const float*)d_in[6];
    const float* g0 = (const float*)d_in[7];
    const float* b0 = (const float*)d_in[8];
    const float* m0 = (const float*)d_in[9];
    const float* v0 = (const float*)d_in[10];
    const float* w1 = (const float*)d_in[11];
    const float* g1 = (const float*)d_in[12];
    const float* b1 = (const float*)d_in[13];
    const float* m1 = (const float*)d_in[14];
    const float* v1 = (const float*)d_in[15];
    const float* w2 = (const float*)d_in[16];
    const float* b2 = (const float*)d_in[17];
    float* out = (float*)d_out;

    float*  ws    = (float*)d_ws;
    float4* plane = (float4*)(ws + WS_PAIR_OFF);

    k_setup<<<1, 64, 0, stream>>>(dmin, dmax,
                                  w0, g0, b0, m0, v0,
                                  w1, g1, b1, m1, v1,
                                  w2, b2, ws);

    // k1: 5120 blocks over (pixel, depth-pair); k2: 2560 blocks over
    // (pixel, neighbor-half). All kernels map pixel p -> XCD p/40960, so
    // the XCD that writes a pair band is the XCD that gathers from it.
    k_s_xnorm<<<5120, 256, 0, stream>>>(cost, dsamp, ws, plane);
    k_aggregate<<<2560, 256, 0, stream>>>(grid, fweight, plane, out);
}